// Round 1
// baseline (86.123 us; speedup 1.0000x reference)
//
#include <hip/hip_runtime.h>

// QuantumKernelMethod: analytic collapse.
//   out[x,y] = M^2,  M = prod_i cos((x_i - y_i)/2)
//            = Cx * Cy * prod_i (1 + tx_i * ty_i),
//   tx = tan(x/2), ty = tan(y/2), Cx = prod cos(x/2), Cy = prod cos(y/2).
// (params provably unused: RZ phases / CNOT permutation are sample-
// independent and cancel in |<x|y>|^2.)
//
// Ladder: R1 100.8 -> R3 fused 89.4 -> R5 tan-X+packed CPT=2 83.0 ->
// R6 CPT=4+nt+512blk 87.2 -> R7 two-kernel 88.0 -> R8 clean CPT=4 82.5.
// R9 THEORY: timed graph = ~45us poison fill (fixed) + ~37us kernel.
// Kernel write-roofline is ~11us -> latency-bound. Root cause: Y held as
// cy+sy packed pairs = 80 VGPRs -> est >128 total -> 2 waves/SIMD.
// Fix: symmetric tan form halves Y state (ty[10][2] + packed Cy = 44
// VGPRs), Y loaded as 10 contiguous float4 (was 40 scalar dwords),
// X staging one-thread-per-row (drops cxa LDS + one barrier).
// Predict: VGPR ~150->~110, occupancy 2x, total 82.5 -> ~66-71us.

#define NS 4096   // samples per set
#define NW 10     // wires
#define ROWS 16   // rows per block
#define CPT 4     // columns per thread (two packed pairs, one b128 store)

typedef float v2f __attribute__((ext_vector_type(2)));
typedef float v4f __attribute__((ext_vector_type(4)));

static __device__ inline v2f splat2(float x) { v2f v; v.x = x; v.y = x; return v; }

__global__ __launch_bounds__(256) void qkm_fused(
    const float* __restrict__ X, const float* __restrict__ Y,
    float* __restrict__ out) {
    __shared__ float xrow[ROWS][12];   // per row: tx[0..9], Cx, pad (48 B)

    const int col  = (blockIdx.x * 256 + threadIdx.x) * CPT;
    const int row0 = blockIdx.y * ROWS;

    // ---- Y: this thread's 4 rows are 40 contiguous floats, 16B-aligned.
    //      Load as 10 float4, unpack with static indices (stays in regs).
    float yv[40];
    {
        const float4* src = reinterpret_cast<const float4*>(Y + (size_t)col * NW);
#pragma unroll
        for (int k = 0; k < 10; ++k) {
            float4 q = src[k];
            yv[4 * k + 0] = q.x; yv[4 * k + 1] = q.y;
            yv[4 * k + 2] = q.z; yv[4 * k + 3] = q.w;
        }
    }

    // ---- X staging: one thread per row (tiny: 10 sincos), single barrier.
    if (threadIdx.x < ROWS) {
        const int r = threadIdx.x;
        float Cx = 1.0f;
#pragma unroll
        for (int w = 0; w < NW; ++w) {
            float s, c;
            __sincosf(0.5f * X[(row0 + r) * NW + w], &s, &c);
            float cs = (fabsf(c) < 1e-30f) ? copysignf(1e-30f, c) : c;
            xrow[r][w] = __fdividef(s, cs);   // tx = tan(x/2)
            Cx *= cs;
        }
        xrow[r][NW] = Cx;
    }

    // ---- Y fragments: ty = tan(y/2) as packed pairs, Cy = prod cos(y/2).
    //      44 VGPRs of persistent Y state (was 80 with cy+sy form).
    v2f ty[NW][2], cyp[2];
    cyp[0] = splat2(1.0f);
    cyp[1] = splat2(1.0f);
#pragma unroll
    for (int j = 0; j < 2; ++j) {
#pragma unroll
        for (int w = 0; w < NW; ++w) {
            float s0, c0, s1, c1;
            __sincosf(0.5f * yv[(2 * j) * NW + w], &s0, &c0);
            __sincosf(0.5f * yv[(2 * j + 1) * NW + w], &s1, &c1);
            c0 = (fabsf(c0) < 1e-30f) ? copysignf(1e-30f, c0) : c0;
            c1 = (fabsf(c1) < 1e-30f) ? copysignf(1e-30f, c1) : c1;
            v2f t; t.x = __fdividef(s0, c0); t.y = __fdividef(s1, c1);
            ty[w][j] = t;
            v2f c; c.x = c0; c.y = c1;
            cyp[j] = cyp[j] * c;
        }
    }

    __syncthreads();

    const v2f one = splat2(1.0f);
#pragma unroll 2
    for (int r = 0; r < ROWS; ++r) {
        float a[12];                          // tx[0..9], Cx  (3x ds_read_b128)
        *reinterpret_cast<float4*>(&a[0]) = *reinterpret_cast<const float4*>(&xrow[r][0]);
        *reinterpret_cast<float4*>(&a[4]) = *reinterpret_cast<const float4*>(&xrow[r][4]);
        *reinterpret_cast<float4*>(&a[8]) = *reinterpret_cast<const float4*>(&xrow[r][8]);
        const v2f cc = splat2(a[NW]);         // Cx
        v2f p0 = cc * cyp[0];                 // start from Cx*Cy
        v2f p1 = cc * cyp[1];
#pragma unroll
        for (int w = 0; w < NW; ++w) {
            const v2f t = splat2(a[w]);
            p0 = p0 * (one + t * ty[w][0]);   // v_pk_fma + v_pk_mul
            p1 = p1 * (one + t * ty[w][1]);
        }
        v4f o;
        o.x = p0.x * p0.x; o.y = p0.y * p0.y;
        o.z = p1.x * p1.x; o.w = p1.y * p1.y;
        *reinterpret_cast<v4f*>(out + (size_t)(row0 + r) * NS + col) = o;
    }
}

extern "C" void kernel_launch(void* const* d_in, const int* in_sizes, int n_in,
                              void* d_out, int out_size, void* d_ws, size_t ws_size,
                              hipStream_t stream) {
    const float* X = (const float*)d_in[0];   // (4096, 10)
    const float* Y = (const float*)d_in[1];   // (4096, 10)
    // d_in[2] = params (4,10): unused (phases cancel in |<x|y>|^2).
    float* out = (float*)d_out;               // (4096, 4096) fp32

    dim3 grid(NS / (256 * CPT), NS / ROWS);   // (4, 256) = 1024 blocks
    qkm_fused<<<grid, 256, 0, stream>>>(X, Y, out);
}

// Round 2
// 82.768 us; speedup vs baseline: 1.0405x; 1.0405x over previous
//
#include <hip/hip_runtime.h>

// QuantumKernelMethod: analytic collapse.
//   out[x,y] = M^2,  M = prod_i cos((x_i - y_i)/2)
//            = prod_i [cos(x_i/2)cos(y_i/2) + sin(x_i/2)sin(y_i/2)]
// (params provably unused: RZ phases / CNOT permutation are sample-
// independent and cancel in |<x|y>|^2.)
//
// Ladder: R1 100.8 -> R3 fused 89.4 -> R5 tan-X+packed CPT=2 83.0 ->
// R6 CPT=4+nt 87.2 -> R7 two-kernel 88.0 -> R8 clean CPT=4 82.5 (best) ->
// R9 tan-Y low-VGPR 86.1 (regressed: +40 rcp/guards on Y; fills also +2us
// session noise; VGPR cut proved irrelevant — grid caps at 16 waves/CU).
// R10 UNIFIED THEORY: timed graph = fill(268MB) + kernel(67MB w) +
// result copy(134MB) = ~470MB @ ~5.9TB/s achieved => ~80us HBM floor.
// Kernel-side changes can only shave its non-overlapped setup. This
// round: merge best pieces — R8's cy/sy Y-form (no Y divides/guards),
// R9's float4 Y loads (10 dwordx4 vs 40 dwords) and single-barrier
// X staging (no cxa LDS, one __syncthreads). Predict 81-83us; that is
// within a few % of the traffic floor -> declare roofline if confirmed.

#define NS 4096   // samples per set
#define NW 10     // wires
#define ROWS 16   // rows per block
#define CPT 4     // columns per thread (two packed pairs, one b128 store)

typedef float v2f __attribute__((ext_vector_type(2)));
typedef float v4f __attribute__((ext_vector_type(4)));

static __device__ inline v2f splat2(float x) { v2f v; v.x = x; v.y = x; return v; }

__global__ __launch_bounds__(256) void qkm_fused(
    const float* __restrict__ X, const float* __restrict__ Y,
    float* __restrict__ out) {
    __shared__ float xrow[ROWS][12];   // per row: tx[0..9], Cx, pad (48 B)

    const int col  = (blockIdx.x * 256 + threadIdx.x) * CPT;
    const int row0 = blockIdx.y * ROWS;

    // ---- Y: this thread's 4 rows are 40 contiguous floats, 16B-aligned.
    //      Load as 10 float4 (issued early; L2-hot: Y totals 160 KB).
    float yv[40];
    {
        const float4* src = reinterpret_cast<const float4*>(Y + (size_t)col * NW);
#pragma unroll
        for (int k = 0; k < 10; ++k) {
            float4 q = src[k];
            yv[4 * k + 0] = q.x; yv[4 * k + 1] = q.y;
            yv[4 * k + 2] = q.z; yv[4 * k + 3] = q.w;
        }
    }

    // ---- X staging: one thread per row (10 sincos each), single barrier.
    if (threadIdx.x < ROWS) {
        const int r = threadIdx.x;
        float Cx = 1.0f;
#pragma unroll
        for (int w = 0; w < NW; ++w) {
            float s, c;
            __sincosf(0.5f * X[(row0 + r) * NW + w], &s, &c);
            // |cos(x/2)| >= ~4e-8 for representable x in [0,2pi]; guard anyway.
            float cs = (fabsf(c) < 1e-30f) ? copysignf(1e-30f, c) : c;
            xrow[r][w] = __fdividef(s, cs);   // tx = tan(x/2)
            Cx *= cs;
        }
        xrow[r][NW] = Cx;
    }

    // ---- Y fragments: (cos,sin) of half-angles as packed pairs.
    //      cy/sy form: no divides, no guards on the Y side (R8 lesson).
    v2f cy[NW][2], sy[NW][2];
#pragma unroll
    for (int j = 0; j < 2; ++j) {
#pragma unroll
        for (int w = 0; w < NW; ++w) {
            float s0, c0, s1, c1;
            __sincosf(0.5f * yv[(2 * j) * NW + w], &s0, &c0);
            __sincosf(0.5f * yv[(2 * j + 1) * NW + w], &s1, &c1);
            v2f c; c.x = c0; c.y = c1;
            v2f s; s.x = s0; s.y = s1;
            cy[w][j] = c; sy[w][j] = s;
        }
    }

    __syncthreads();

#pragma unroll 2
    for (int r = 0; r < ROWS; ++r) {
        float a[12];                          // tx[0..9], Cx  (3x ds_read_b128)
        *reinterpret_cast<float4*>(&a[0]) = *reinterpret_cast<const float4*>(&xrow[r][0]);
        *reinterpret_cast<float4*>(&a[4]) = *reinterpret_cast<const float4*>(&xrow[r][4]);
        *reinterpret_cast<float4*>(&a[8]) = *reinterpret_cast<const float4*>(&xrow[r][8]);
        const v2f cc = splat2(a[NW]);         // Cx
        v2f p0 = cc;
        v2f p1 = cc;
#pragma unroll
        for (int w = 0; w < NW; ++w) {
            const v2f t = splat2(a[w]);
            p0 = p0 * (cy[w][0] + t * sy[w][0]);   // v_pk_fma + v_pk_mul
            p1 = p1 * (cy[w][1] + t * sy[w][1]);
        }
        v4f o;
        o.x = p0.x * p0.x; o.y = p0.y * p0.y;
        o.z = p1.x * p1.x; o.w = p1.y * p1.y;
        *reinterpret_cast<v4f*>(out + (size_t)(row0 + r) * NS + col) = o;
    }
}

extern "C" void kernel_launch(void* const* d_in, const int* in_sizes, int n_in,
                              void* d_out, int out_size, void* d_ws, size_t ws_size,
                              hipStream_t stream) {
    const float* X = (const float*)d_in[0];   // (4096, 10)
    const float* Y = (const float*)d_in[1];   // (4096, 10)
    // d_in[2] = params (4,10): unused (phases cancel in |<x|y>|^2).
    float* out = (float*)d_out;               // (4096, 4096) fp32

    dim3 grid(NS / (256 * CPT), NS / ROWS);   // (4, 256) = 1024 blocks
    qkm_fused<<<grid, 256, 0, stream>>>(X, Y, out);
}